// Round 1
// baseline (432.753 us; speedup 1.0000x reference)
//
#include <hip/hip_runtime.h>

#define H_  12
#define S_  3136
#define D_  768
#define NP_ 196

typedef unsigned short u16;
typedef __bf16 bf16_t;
typedef bf16_t bf16x8 __attribute__((ext_vector_type(8)));
typedef float  f32x4  __attribute__((ext_vector_type(4)));
typedef u16    u16x4  __attribute__((ext_vector_type(4)));

typedef const __attribute__((address_space(1))) void* gas_ptr;
typedef __attribute__((address_space(3))) void* las_ptr;

__device__ __forceinline__ u16 f2bf(float f) {
    unsigned u = __float_as_uint(f);
    u += 0x7fffu + ((u >> 16) & 1u);   // RNE
    return (u16)(u >> 16);
}

__device__ __forceinline__ f32x4 mfma16(bf16x8 a, bf16x8 b, f32x4 c) {
    return __builtin_amdgcn_mfma_f32_16x16x32_bf16(a, b, c, 0, 0, 0);
}

__device__ __forceinline__ void gld16(const void* g, void* l) {
    __builtin_amdgcn_global_load_lds((gas_ptr)g, (las_ptr)l, 16, 0, 0);
}

// ---------------------------------------------------------------- convert
__global__ __launch_bounds__(256) void cvt7(
    const float* __restrict__ s0, const float* __restrict__ s1,
    const float* __restrict__ s2, const float* __restrict__ s3,
    const float* __restrict__ s4, const float* __restrict__ s5,
    const float* __restrict__ s6,
    u16* __restrict__ xb, u16* __restrict__ wb)
{
    const int which = blockIdx.y;
    const float* s; u16* d; int n;
    if (which < 3) {
        s = (which == 0) ? s0 : (which == 1) ? s1 : s2;
        d = xb + (size_t)which * 2408448; n = 2408448;
    } else {
        const int w = which - 3;
        s = (w == 0) ? s3 : (w == 1) ? s4 : (w == 2) ? s5 : s6;
        d = wb + (size_t)w * 589824; n = 589824;
    }
    const int i = (blockIdx.x * 256 + threadIdx.x) * 4;
    if (i >= n) return;
    const float4 v = *(const float4*)(s + i);
    u16x4 o = { f2bf(v.x), f2bf(v.y), f2bf(v.z), f2bf(v.w) };
    *(u16x4*)(d + i) = o;
}

// ---------------------------------------------------------------- QKV GEMM
// y[s,o] = sum_k X[s,k]*W[o,k] + b[o]   (BT layout), 128x128 tile, BK=64
__global__ __launch_bounds__(256) void qkv_gemm(
    const u16* __restrict__ Xall, const u16* __restrict__ Wall,
    const float* __restrict__ bq, const float* __restrict__ bk,
    const float* __restrict__ bv,
    float* __restrict__ yout,          // qh|kh|vh fp32 sections, [h][s][64]
    u16* __restrict__ qkbf,            // qh_bf|kh_bf, [h][s][64]
    u16* __restrict__ vtbf)            // vt_bf [h][64][s]
{
    __shared__ u16 Alds[128][64];
    __shared__ u16 Blds[128][64];
    const int tid = threadIdx.x;
    const int z  = blockIdx.z;
    const int m0 = blockIdx.x * 128;
    const int n0 = blockIdx.y * 128;
    const u16* X = Xall + (size_t)z * (size_t)(S_ * D_);
    const u16* W = Wall + (size_t)z * (size_t)(D_ * D_);
    const int lane = tid & 63, wid = tid >> 6;
    const int l15 = lane & 15, lhi = lane >> 4;
    const int wm = wid >> 1, wn = wid & 1;

    const f32x4 zf = {0.f, 0.f, 0.f, 0.f};
    f32x4 acc[4][4];
#pragma unroll
    for (int mi = 0; mi < 4; ++mi)
#pragma unroll
        for (int ni = 0; ni < 4; ++ni) acc[mi][ni] = zf;

    for (int kt = 0; kt < 12; ++kt) {
        const int k0 = kt * 64;
#pragma unroll
        for (int it = 0; it < 4; ++it) {
            const int e   = it * 256 + tid;
            const int row = e >> 3;
            const int col = (e & 7) << 3;
            const int lbase = __builtin_amdgcn_readfirstlane((it * 256 + (tid & 192)) << 3);
            int ar = m0 + row; if (ar > S_ - 1) ar = S_ - 1;   // clamp tail tile
            gld16(X + (size_t)ar * D_ + k0 + col, &Alds[0][0] + lbase);
            gld16(W + (size_t)(n0 + row) * D_ + k0 + col, &Blds[0][0] + lbase);
        }
        __syncthreads();
#pragma unroll
        for (int ks = 0; ks < 2; ++ks) {
            bf16x8 af[4], bfv[4];
#pragma unroll
            for (int mi = 0; mi < 4; ++mi)
                af[mi] = *(const bf16x8*)&Alds[wm*64 + mi*16 + l15][ks*32 + lhi*8];
#pragma unroll
            for (int ni = 0; ni < 4; ++ni)
                bfv[ni] = *(const bf16x8*)&Blds[wn*64 + ni*16 + l15][ks*32 + lhi*8];
#pragma unroll
            for (int mi = 0; mi < 4; ++mi)
#pragma unroll
                for (int ni = 0; ni < 4; ++ni)
                    acc[mi][ni] = mfma16(af[mi], bfv[ni], acc[mi][ni]);
        }
        __syncthreads();
    }

    const float* bias = (z == 0) ? bq : (z == 1) ? bk : bv;
    float* ysec = yout + (size_t)z * 2408448;
#pragma unroll
    for (int ni = 0; ni < 4; ++ni) {
        const int o = n0 + wn*64 + ni*16 + l15;
        const int head = o >> 6, dd = o & 63;
        const float bb = bias[o];
#pragma unroll
        for (int mi = 0; mi < 4; ++mi) {
            const int s0r = m0 + wm*64 + mi*16 + lhi*4;
            if (s0r >= S_) continue;
            const float y0 = acc[mi][ni][0] + bb;
            const float y1 = acc[mi][ni][1] + bb;
            const float y2 = acc[mi][ni][2] + bb;
            const float y3 = acc[mi][ni][3] + bb;
            float* yp = ysec + (size_t)head * (S_*64) + (size_t)s0r * 64 + dd;
            yp[0] = y0; yp[64] = y1; yp[128] = y2; yp[192] = y3;
            if (z < 2) {
                u16* qp = qkbf + (size_t)z * 2408448 + (size_t)head * (S_*64)
                        + (size_t)s0r * 64 + dd;
                qp[0] = f2bf(y0); qp[64] = f2bf(y1);
                qp[128] = f2bf(y2); qp[192] = f2bf(y3);
            } else {
                u16x4 pk = { f2bf(y0), f2bf(y1), f2bf(y2), f2bf(y3) };
                *(u16x4*)&vtbf[((size_t)head * 64 + dd) * S_ + s0r] = pk;
            }
        }
    }
}

// ---------------------------------------------------------------- attention
// One block = (head, 64 q-rows). 4 waves x 16 rows. Two-pass exact softmax.
__global__ __launch_bounds__(256) void attn_k(
    const u16* __restrict__ qh, const u16* __restrict__ kh,
    const u16* __restrict__ vt, float* __restrict__ attn,
    u16* __restrict__ oh)
{
    __shared__ u16 P_lds[4][16][72];   // per-wave P strip, padded (144B row)
    const int tid  = threadIdx.x;
    const int wid  = tid >> 6, lane = tid & 63;
    const int l15  = lane & 15, lhi = lane >> 4;
    const int bid  = blockIdx.x;
    const int h    = bid / 49;
    const int qt   = bid - h * 49;
    const int q0   = qt << 6;
    float* attnh = attn + (size_t)h * S_ * S_;

    const int fql  = (q0 + 63) / NP_;
    const int Lmax = (fql + 1) * NP_;          // max allowed col (excl) in tile
    const int nkt  = (Lmax + 63) >> 6;         // k-tiles to compute

    // bulk zero-fill of fully-masked tail columns (output is poisoned)
    {
        const int zs = nkt << 6;
        const int n4 = (S_ - zs) >> 2;
        if (n4 > 0) {
            const float4 z4 = make_float4(0.f, 0.f, 0.f, 0.f);
            for (int row = 0; row < 64; ++row) {
                float4* rp = (float4*)(attnh + (size_t)(q0 + row) * S_ + zs);
                for (int c = tid; c < n4; c += 256) rp[c] = z4;
            }
        }
    }

    // Q fragments stay in registers for the whole block
    const u16* qbase = qh + ((size_t)h * S_ + q0 + wid*16 + l15) * 64 + lhi*8;
    const bf16x8 aq0 = *(const bf16x8*)(qbase);
    const bf16x8 aq1 = *(const bf16x8*)(qbase + 32);

    const int qrow = q0 + wid*16 + lhi*4;      // this lane's 4 stat rows
    int lim[4];
#pragma unroll
    for (int r = 0; r < 4; ++r) lim[r] = ((qrow + r) / NP_ + 1) * NP_;

    float m[4], l[4];
#pragma unroll
    for (int r = 0; r < 4; ++r) { m[r] = -1e30f; l[r] = 0.0f; }

    const u16* khh = kh + (size_t)h * S_ * 64;
    const u16* vth = vt + (size_t)h * 64 * S_;
    const f32x4 zf = {0.f, 0.f, 0.f, 0.f};

    // ---- pass A: row max + denominator (scores recomputed, never stored)
    for (int kt = 0; kt < nkt; ++kt) {
        const int k0 = kt << 6;
        f32x4 sc[4];
#pragma unroll
        for (int ni = 0; ni < 4; ++ni) sc[ni] = zf;
        const u16* kb = khh + (size_t)(k0 + l15) * 64 + lhi * 8;
#pragma unroll
        for (int ni = 0; ni < 4; ++ni) {
            const bf16x8 b0 = *(const bf16x8*)(kb + ni * 1024);
            const bf16x8 b1 = *(const bf16x8*)(kb + ni * 1024 + 32);
            sc[ni] = mfma16(aq0, b0, sc[ni]);
            sc[ni] = mfma16(aq1, b1, sc[ni]);
        }
#pragma unroll
        for (int ni = 0; ni < 4; ++ni) {
            const int kc = k0 + ni*16 + l15;
#pragma unroll
            for (int r = 0; r < 4; ++r) {
                const float s = sc[ni][r] * 0.125f;
                sc[ni][r] = (kc < lim[r]) ? s : -1e30f;
            }
        }
#pragma unroll
        for (int r = 0; r < 4; ++r) {
            float tm = fmaxf(fmaxf(sc[0][r], sc[1][r]), fmaxf(sc[2][r], sc[3][r]));
#pragma unroll
            for (int off = 8; off; off >>= 1) tm = fmaxf(tm, __shfl_xor(tm, off));
            const float mn = fmaxf(m[r], tm);
            float sum = __expf(sc[0][r] - mn) + __expf(sc[1][r] - mn)
                      + __expf(sc[2][r] - mn) + __expf(sc[3][r] - mn);
#pragma unroll
            for (int off = 8; off; off >>= 1) sum += __shfl_xor(sum, off);
            l[r] = l[r] * __expf(m[r] - mn) + sum;
            m[r] = mn;
        }
    }

    float rl[4];
#pragma unroll
    for (int r = 0; r < 4; ++r) rl[r] = 1.0f / l[r];

    f32x4 ov[4];
#pragma unroll
    for (int ni = 0; ni < 4; ++ni) ov[ni] = zf;

    // ---- pass B: recompute scores, write P, accumulate O = P @ V
    for (int kt = 0; kt < nkt; ++kt) {
        const int k0 = kt << 6;
        f32x4 sc[4];
#pragma unroll
        for (int ni = 0; ni < 4; ++ni) sc[ni] = zf;
        const u16* kb = khh + (size_t)(k0 + l15) * 64 + lhi * 8;
#pragma unroll
        for (int ni = 0; ni < 4; ++ni) {
            const bf16x8 b0 = *(const bf16x8*)(kb + ni * 1024);
            const bf16x8 b1 = *(const bf16x8*)(kb + ni * 1024 + 32);
            sc[ni] = mfma16(aq0, b0, sc[ni]);
            sc[ni] = mfma16(aq1, b1, sc[ni]);
        }
        u16 pb[4][4];
#pragma unroll
        for (int ni = 0; ni < 4; ++ni) {
            const int kc = k0 + ni*16 + l15;
#pragma unroll
            for (int r = 0; r < 4; ++r) {
                const float s  = sc[ni][r] * 0.125f;
                const float sm = (kc < lim[r]) ? s : -1e30f;
                const float pv = __expf(sm - m[r]) * rl[r];   // masked -> 0
                attnh[(size_t)(qrow + r) * S_ + kc] = pv;
                pb[ni][r] = f2bf(pv);
            }
        }
        __syncthreads();   // protect P_lds WAR vs previous iteration
#pragma unroll
        for (int ni = 0; ni < 4; ++ni)
#pragma unroll
            for (int r = 0; r < 4; ++r)
                P_lds[wid][lhi*4 + r][ni*16 + l15] = pb[ni][r];
        __syncthreads();
#pragma unroll
        for (int ks = 0; ks < 2; ++ks) {
            const bf16x8 pa = *(const bf16x8*)&P_lds[wid][l15][ks*32 + lhi*8];
            const u16* vb = vth + (size_t)l15 * S_ + k0 + ks*32 + lhi*8;
#pragma unroll
            for (int ni = 0; ni < 4; ++ni) {
                const bf16x8 b = *(const bf16x8*)(vb + (size_t)(ni*16) * S_);
                ov[ni] = mfma16(pa, b, ov[ni]);
            }
        }
    }

    // O strip -> bf16 concat-head layout for the output projection
#pragma unroll
    for (int ni = 0; ni < 4; ++ni)
#pragma unroll
        for (int r = 0; r < 4; ++r)
            oh[(size_t)(qrow + r) * D_ + h*64 + ni*16 + l15] = f2bf(ov[ni][r]);
}

// ---------------------------------------------------------------- out proj
__global__ __launch_bounds__(256) void out_gemm(
    const u16* __restrict__ A,       // oh bf16 [S][768]
    const u16* __restrict__ W,       // Wo bf16 [768][768] (BT)
    const float* __restrict__ bo,
    float* __restrict__ out)         // [S][768]
{
    __shared__ u16 Alds[128][64];
    __shared__ u16 Blds[128][64];
    const int tid = threadIdx.x;
    const int m0 = blockIdx.x * 128;
    const int n0 = blockIdx.y * 128;
    const int lane = tid & 63, wid = tid >> 6;
    const int l15 = lane & 15, lhi = lane >> 4;
    const int wm = wid >> 1, wn = wid & 1;

    const f32x4 zf = {0.f, 0.f, 0.f, 0.f};
    f32x4 acc[4][4];
#pragma unroll
    for (int mi = 0; mi < 4; ++mi)
#pragma unroll
        for (int ni = 0; ni < 4; ++ni) acc[mi][ni] = zf;

    for (int kt = 0; kt < 12; ++kt) {
        const int k0 = kt * 64;
#pragma unroll
        for (int it = 0; it < 4; ++it) {
            const int e   = it * 256 + tid;
            const int row = e >> 3;
            const int col = (e & 7) << 3;
            const int lbase = __builtin_amdgcn_readfirstlane((it * 256 + (tid & 192)) << 3);
            int ar = m0 + row; if (ar > S_ - 1) ar = S_ - 1;
            gld16(A + (size_t)ar * D_ + k0 + col, &Alds[0][0] + lbase);
            gld16(W + (size_t)(n0 + row) * D_ + k0 + col, &Blds[0][0] + lbase);
        }
        __syncthreads();
#pragma unroll
        for (int ks = 0; ks < 2; ++ks) {
            bf16x8 af[4], bfv[4];
#pragma unroll
            for (int mi = 0; mi < 4; ++mi)
                af[mi] = *(const bf16x8*)&Alds[wm*64 + mi*16 + l15][ks*32 + lhi*8];
#pragma unroll
            for (int ni = 0; ni < 4; ++ni)
                bfv[ni] = *(const bf16x8*)&Blds[wn*64 + ni*16 + l15][ks*32 + lhi*8];
#pragma unroll
            for (int mi = 0; mi < 4; ++mi)
#pragma unroll
                for (int ni = 0; ni < 4; ++ni)
                    acc[mi][ni] = mfma16(af[mi], bfv[ni], acc[mi][ni]);
        }
        __syncthreads();
    }

#pragma unroll
    for (int ni = 0; ni < 4; ++ni) {
        const int o = n0 + wn*64 + ni*16 + l15;
        const float bb = bo[o];
#pragma unroll
        for (int mi = 0; mi < 4; ++mi) {
            const int s0r = m0 + wm*64 + mi*16 + lhi*4;
            if (s0r >= S_) continue;
            float* yp = out + (size_t)s0r * D_ + o;
            yp[0]       = acc[mi][ni][0] + bb;
            yp[D_]      = acc[mi][ni][1] + bb;
            yp[2 * D_]  = acc[mi][ni][2] + bb;
            yp[3 * D_]  = acc[mi][ni][3] + bb;
        }
    }
}

// ---------------------------------------------------------------- launcher
extern "C" void kernel_launch(void* const* d_in, const int* in_sizes, int n_in,
                              void* d_out, int out_size, void* d_ws, size_t ws_size,
                              hipStream_t stream) {
    const float* query = (const float*)d_in[0];
    const float* key_  = (const float*)d_in[1];
    const float* value = (const float*)d_in[2];
    const float* Wq = (const float*)d_in[3];
    const float* bq = (const float*)d_in[4];
    const float* Wk = (const float*)d_in[5];
    const float* bk = (const float*)d_in[6];
    const float* Wv = (const float*)d_in[7];
    const float* bv = (const float*)d_in[8];
    const float* Wo = (const float*)d_in[9];
    const float* bo = (const float*)d_in[10];

    float* out    = (float*)d_out;
    float* qkvh_f = out;                 // qh|kh|vh [h][s][64] x3
    float* attn_f = out + 7225344;       // [h][s][s]
    float* out_f  = out + 125239296;     // [s][768]

    char* ws = (char*)d_ws;
    u16* x_bf  = (u16*)(ws + 0);         // 3 x S*768 bf16
    u16* w_bf  = (u16*)(ws + 14450688);  // 4 x 768*768 bf16 (q,k,v,o)
    u16* qk_bf = (u16*)(ws + 19169280);  // qh_bf | kh_bf
    u16* vt_bf = (u16*)(ws + 28803072);  // [h][64][s]
    u16* oh_bf = (u16*)(ws + 33619968);  // [s][768]

    cvt7<<<dim3(2352, 7), 256, 0, stream>>>(query, key_, value, Wq, Wk, Wv, Wo,
                                            x_bf, w_bf);
    qkv_gemm<<<dim3(25, 6, 3), 256, 0, stream>>>(x_bf, w_bf, bq, bk, bv,
                                                 qkvh_f, qk_bf, vt_bf);
    attn_k<<<dim3(588), 256, 0, stream>>>(qk_bf, qk_bf + 2408448, vt_bf,
                                          attn_f, oh_bf);
    out_gemm<<<dim3(25, 6), 256, 0, stream>>>(oh_bf, w_bf + 3 * 589824, bo, out_f);
}